// Round 14
// baseline (984.360 us; speedup 1.0000x reference)
//
#include <hip/hip_runtime.h>
#include <math.h>

#define B_ 8
#define N_ 20000
#define E_ 40000
#define H_ 128
#define L_ 4
#define A_ 4
#define MRS 136   // fp16 LDS row stride (128+8), edge + node + out kernels
#define EPB 64    // edges per block (2 waves x 32 rows)
#define NPB 64    // nodes per block (4 waves x 16 rows)

// compiler-only memory fence: orders LDS ops across phases without s_barrier
#define WFENCE __asm__ __volatile__("" ::: "memory")

typedef _Float16 f16x8 __attribute__((ext_vector_type(8)));
typedef _Float16 f16x4v __attribute__((ext_vector_type(4)));
typedef float f32x4 __attribute__((ext_vector_type(4)));

// silu via raw v_rcp_f32 (~1 ulp) — avoids the IEEE fdiv expansion (~11 VALU inst)
__device__ __forceinline__ float silu_f(float x) {
    return x * __builtin_amdgcn_rcpf(1.f + __expf(-x));
}

// ---------------- setup kernels ----------------

__global__ void k_zero(int* __restrict__ deg, int* __restrict__ cursor) {
    int i = blockIdx.x * 256 + threadIdx.x;
    if (i < N_) { deg[i] = 0; cursor[i] = 0; }
}

__global__ void k_deg(const int* __restrict__ bond, int* __restrict__ deg) {
    int e = blockIdx.x * 256 + threadIdx.x;
    if (e < E_) {
        atomicAdd(&deg[bond[2 * e]], 1);
        atomicAdd(&deg[bond[2 * e + 1]], 1);
    }
}

__global__ void k_scan(const int* __restrict__ deg, int* __restrict__ indptr) {
    __shared__ int sums[1024];
    const int CH = (N_ + 1023) / 1024;  // 20
    int t = threadIdx.x;
    int s0 = t * CH;
    int s1 = min(s0 + CH, N_);
    int s = 0;
    for (int i = s0; i < s1; ++i) s += deg[i];
    sums[t] = s;
    __syncthreads();
    for (int off = 1; off < 1024; off <<= 1) {
        int v = (t >= off) ? sums[t - off] : 0;
        __syncthreads();
        sums[t] += v;
        __syncthreads();
    }
    int base = (t > 0) ? sums[t - 1] : 0;
    int run = base;
    for (int i = s0; i < s1; ++i) { indptr[i] = run; run += deg[i]; }
    if (s1 == N_ && s0 < N_) indptr[N_] = run;
}

__global__ void k_fill(const int* __restrict__ bond, const int* __restrict__ indptr,
                       int* __restrict__ cursor, int* __restrict__ adj) {
    int e = blockIdx.x * 256 + threadIdx.x;
    if (e < E_) {
        int s = bond[2 * e], d = bond[2 * e + 1];
        int ps = indptr[s] + atomicAdd(&cursor[s], 1);
        adj[ps] = (e << 1);        // node is src -> sign -
        int pd = indptr[d] + atomicAdd(&cursor[d], 1);
        adj[pd] = (e << 1) | 1;    // node is dst -> sign +
    }
}

// Convert W[K][128] fp32 -> B-fragment-layout fp16 for mfma_f32_16x16x32_f16.
// blockIdx.y = layer; strides passed per weight type.
__global__ void k_wprepL(const float* __restrict__ W, _Float16* __restrict__ Wf,
                         int K, int wstride) {
    int l = blockIdx.y;
    const float* Wl = W + (size_t)l * wstride;
    _Float16* Wfl = Wf + (size_t)l * K * 128;
    int idx = blockIdx.x * 256 + threadIdx.x;
    if (idx >= K * 128) return;
    int j = idx & 7, lane = (idx >> 3) & 63, nt = (idx >> 9) & 7, kt = idx >> 12;
    int k = kt * 32 + (lane >> 4) * 8 + j;
    int n = nt * 16 + (lane & 15);
    Wfl[idx] = (_Float16)Wl[k * 128 + n];
}

__global__ void k_temb(const float* __restrict__ tv,
                       const float* __restrict__ W1, const float* __restrict__ b1,
                       const float* __restrict__ W2, const float* __restrict__ b2,
                       float* __restrict__ t_emb) {
    __shared__ float te[64];
    __shared__ float h1[128];
    int b = blockIdx.x;
    int tid = threadIdx.x;
    float tval = tv[b];
    if (tid < 32) {
        float fr = __expf((float)tid * (-logf(10000.f) / 31.f));
        float a = tval * fr;
        te[tid] = sinf(a);
        te[tid + 32] = cosf(a);
    }
    __syncthreads();
    float acc = b1[tid];
    for (int k = 0; k < 64; ++k) acc += te[k] * W1[k * 128 + tid];
    h1[tid] = silu_f(acc);
    __syncthreads();
    float acc2 = b2[tid];
    for (int k = 0; k < 128; ++k) acc2 += h1[k] * W2[k * 128 + tid];
    t_emb[b * 128 + tid] = acc2;
}

__global__ void k_embproj(const float* __restrict__ emb, const float* __restrict__ W,
                          const float* __restrict__ bias, float* __restrict__ outp) {
    int tid = threadIdx.x;       // 512 threads
    int a = tid >> 7, j = tid & 127;
    float acc = bias[j];
    for (int k = 0; k < 128; ++k) acc += emb[a * 128 + k] * W[k * 128 + j];
    outp[a * 128 + j] = acc;
}

__global__ void k_hinit(const int* __restrict__ at, const float* __restrict__ embp,
                        const float* __restrict__ temb, float* __restrict__ h,
                        _Float16* __restrict__ h16) {
    size_t idx4 = (size_t)blockIdx.x * 256 + threadIdx.x;   // over B*N*H/4
    size_t e0 = idx4 * 4;
    int j = (int)(e0 % H_);
    size_t bn = e0 / H_;
    int n = (int)(bn % N_);
    int b = (int)(bn / N_);
    int a = at[n];
    float4 ep = *(const float4*)(embp + a * H_ + j);
    float4 tv = *(const float4*)(temb + b * H_ + j);
    float4 r = make_float4(ep.x + tv.x, ep.y + tv.y, ep.z + tv.z, ep.w + tv.w);
    ((float4*)h)[idx4] = r;
    f16x4v o;
    o[0] = (_Float16)r.x; o[1] = (_Float16)r.y; o[2] = (_Float16)r.z; o[3] = (_Float16)r.w;
    *(f16x4v*)(h16 + e0) = o;
}

__global__ void k_xcopy(const float* __restrict__ x, float* __restrict__ xb) {
    int i = blockIdx.x * 256 + threadIdx.x;  // 480000 exact
    xb[i] = x[i];
}

// ---------------- MFMA GEMM cores (wave-local) ----------------
// Single row-tile (16 rows/wave) — node + out kernels:
template <int RS, int KT>
__device__ __forceinline__ void mfma_gemm(const _Float16* Asw, const _Float16* __restrict__ Wf,
                                          f32x4 (&acc)[8], int ml, int quad, int lane) {
    #pragma unroll
    for (int kt = 0; kt < KT; ++kt) {
        f16x8 a = *(const f16x8*)(Asw + ml * RS + kt * 32 + quad * 8);
        #pragma unroll
        for (int nt = 0; nt < 8; ++nt) {
            f16x8 b = *(const f16x8*)(Wf + (((kt * 8 + nt) * 64 + lane) * 8));
            acc[nt] = __builtin_amdgcn_mfma_f32_16x16x32_f16(a, b, acc[nt], 0, 0, 0);
        }
    }
}

// Two row-tiles (32 rows/wave) sharing each B fragment — edge kernel:
template <int RS, int KT>
__device__ __forceinline__ void mfma_gemm2(const _Float16* Asw, const _Float16* __restrict__ Wf,
                                           f32x4 (&acc)[2][8], int ml, int quad, int lane) {
    #pragma unroll
    for (int kt = 0; kt < KT; ++kt) {
        f16x8 a0 = *(const f16x8*)(Asw + ml * RS + kt * 32 + quad * 8);
        f16x8 a1 = *(const f16x8*)(Asw + (16 + ml) * RS + kt * 32 + quad * 8);
        #pragma unroll
        for (int nt = 0; nt < 8; ++nt) {
            f16x8 b = *(const f16x8*)(Wf + (((kt * 8 + nt) * 64 + lane) * 8));
            acc[0][nt] = __builtin_amdgcn_mfma_f32_16x16x32_f16(a0, b, acc[0][nt], 0, 0, 0);
            acc[1][nt] = __builtin_amdgcn_mfma_f32_16x16x32_f16(a1, b, acc[1][nt], 0, 0, 0);
        }
    }
}

// gather helpers (node kernel): statically-indexed register rows (rule #20 safe)
__device__ __forceinline__ void load_row(f16x8 (&v)[4], const _Float16* mp) {
    #pragma unroll
    for (int j = 0; j < 4; ++j) v[j] = *(const f16x8*)(mp + j * 8);
}
__device__ __forceinline__ void acc_row(float (&ag)[4][8], const f16x8 (&v)[4]) {
    #pragma unroll
    for (int j = 0; j < 4; ++j)
        #pragma unroll
        for (int i = 0; i < 8; ++i) ag[j][i] += (float)v[j][i];
}

// ---------------- per-layer kernels ----------------

// 64 edges/block, 128 threads = 2 waves x 32 rows (R8 structure).
// R11-proven epilogue: upd[e][3] via LDS bounce + coalesced 384B/wave store.
// R13: m16 store after GEMM3's MFMAs (neutral but harmless; kept).
__global__ __launch_bounds__(128, 3) void k_edge_mfma(
    const _Float16* __restrict__ h16, const float* __restrict__ xcur,
    const int* __restrict__ bond,
    const float* __restrict__ Wm1, const float* __restrict__ bm1,
    const _Float16* __restrict__ Wm1f,
    const float* __restrict__ bm2, const _Float16* __restrict__ Wm2f,
    const float* __restrict__ bc1, const _Float16* __restrict__ Wc1f,
    const float* __restrict__ Wc2,
    _Float16* __restrict__ m16, float* __restrict__ upd) {
    __shared__ _Float16 As[EPB * MRS];   // 17408 B
    __shared__ float ds_s[EPB];
    __shared__ float dx_s[EPB], dy_s[EPB], dz_s[EPB];   // +768 B
    __shared__ float u_s[EPB * 3];                      // +768 B
    int tid = threadIdx.x;
    int b = blockIdx.x & 7;              // batch -> XCD locality
    int e0 = (blockIdx.x >> 3) * EPB;    // chunk within batch (0..624)
    size_t be0 = (size_t)b * E_ + e0;

    int el = tid >> 1, q = tid & 1;      // 2 threads/row; rows are wave-own
    int2 sd = ((const int2*)bond)[e0 + el];
    int s = sd.x, d = sd.y;

    // issue BOTH gathers now (T14): ps consumed immediately, pd held across GEMM1a
    const _Float16* hs = h16 + ((size_t)b * N_ + s) * H_ + q * 64;
    const _Float16* hd = h16 + ((size_t)b * N_ + d) * H_ + q * 64;
    f16x8 ps[8], pd[8];
    #pragma unroll
    for (int j = 0; j < 8; ++j) ps[j] = *(const f16x8*)(hs + j * 8);
    #pragma unroll
    for (int j = 0; j < 8; ++j) pd[j] = *(const f16x8*)(hd + j * 8);
    if (q == 0) {
        const float* xs = xcur + ((size_t)b * N_ + s) * 3;
        const float* xd = xcur + ((size_t)b * N_ + d) * 3;
        float dx = xd[0] - xs[0], dy = xd[1] - xs[1], dz = xd[2] - xs[2];
        ds_s[el] = sqrtf(dx * dx + dy * dy + dz * dz);
        dx_s[el] = dx; dy_s[el] = dy; dz_s[el] = dz;
    }
    {   // stage h_src
        _Float16* ap = As + el * MRS + q * 64;
        #pragma unroll
        for (int j = 0; j < 8; ++j) *(f16x8*)(ap + j * 8) = ps[j];
    }
    WFENCE;

    int lane = tid & 63, w = tid >> 6;   // wave owns rows w*32..w*32+31
    int ml = lane & 15, quad = lane >> 4;
    _Float16* Asw = As + w * 32 * MRS;
    const float* wd = Wm1 + 256 * H_;

    f32x4 acc[2][8];
    // acc = bm1 + dist*wd
    #pragma unroll
    for (int nt = 0; nt < 8; ++nt) {
        int col = nt * 16 + ml;
        float bb = bm1[col];
        float ww = wd[col];
        #pragma unroll
        for (int rt = 0; rt < 2; ++rt)
            #pragma unroll
            for (int r = 0; r < 4; ++r)
                acc[rt][nt][r] = bb + ds_s[w * 32 + rt * 16 + quad * 4 + r] * ww;
    }
    mfma_gemm2<MRS, 4>(Asw, Wm1f, acc, ml, quad, lane);              // + h_s @ Wm1[0:128]
    WFENCE;
    {   // restage h_dst from prefetched regs (wave-own rows; in-order DS pipe)
        _Float16* ap = As + el * MRS + q * 64;
        #pragma unroll
        for (int j = 0; j < 8; ++j) *(f16x8*)(ap + j * 8) = pd[j];
    }
    WFENCE;
    mfma_gemm2<MRS, 4>(Asw, Wm1f + 4 * 8 * 64 * 8, acc, ml, quad, lane);  // + h_d @ Wm1[128:256]
    WFENCE;
    // repack m1 = silu(acc) -> As (wave-own rows)
    #pragma unroll
    for (int rt = 0; rt < 2; ++rt)
        #pragma unroll
        for (int nt = 0; nt < 8; ++nt)
            #pragma unroll
            for (int r = 0; r < 4; ++r)
                Asw[(rt * 16 + quad * 4 + r) * MRS + nt * 16 + ml] = (_Float16)silu_f(acc[rt][nt][r]);
    WFENCE;

    // ---- GEMM2: m = silu(m1 @ Wm2 + bm2)
    #pragma unroll
    for (int nt = 0; nt < 8; ++nt) {
        float bb = bm2[nt * 16 + ml];
        #pragma unroll
        for (int rt = 0; rt < 2; ++rt)
            #pragma unroll
            for (int r = 0; r < 4; ++r) acc[rt][nt][r] = bb;
    }
    mfma_gemm2<MRS, 4>(Asw, Wm2f, acc, ml, quad, lane);
    WFENCE;
    // repack m -> As (overwrites m1; this wave's GEMM2 reads are done)
    #pragma unroll
    for (int rt = 0; rt < 2; ++rt)
        #pragma unroll
        for (int nt = 0; nt < 8; ++nt)
            #pragma unroll
            for (int r = 0; r < 4; ++r)
                Asw[(rt * 16 + quad * 4 + r) * MRS + nt * 16 + ml] = (_Float16)silu_f(acc[rt][nt][r]);
    WFENCE;

    // ---- GEMM3: cw = silu(m @ Wc1 + bc1) @ Wc2  (B-loads issue first)
    #pragma unroll
    for (int nt = 0; nt < 8; ++nt) {
        float bb = bc1[nt * 16 + ml];
        #pragma unroll
        for (int rt = 0; rt < 2; ++rt)
            #pragma unroll
            for (int r = 0; r < 4; ++r) acc[rt][nt][r] = bb;
    }
    mfma_gemm2<MRS, 4>(Asw, Wc1f, acc, ml, quad, lane);
    // m16 store: overlaps the Wc2 fold + butterfly below
    #pragma unroll
    for (int j = 0; j < 8; ++j)
        *(f16x8*)(m16 + (be0 + el) * H_ + q * 64 + j * 8) =
            *(const f16x8*)(As + el * MRS + q * 64 + j * 8);
    float part[2][4] = {{0.f, 0.f, 0.f, 0.f}, {0.f, 0.f, 0.f, 0.f}};
    #pragma unroll
    for (int nt = 0; nt < 8; ++nt) {
        float wv = Wc2[nt * 16 + ml];
        #pragma unroll
        for (int rt = 0; rt < 2; ++rt)
            #pragma unroll
            for (int r = 0; r < 4; ++r) part[rt][r] += silu_f(acc[rt][nt][r]) * wv;
    }
    #pragma unroll
    for (int off = 1; off < 16; off <<= 1)
        #pragma unroll
        for (int rt = 0; rt < 2; ++rt)
            #pragma unroll
            for (int r = 0; r < 4; ++r) part[rt][r] += __shfl_xor(part[rt][r], off, 64);
    // upd: LDS bounce (wave-own region [w*96, w*96+96)) then coalesced store.
    if (ml < 3) {
        #pragma unroll
        for (int rt = 0; rt < 2; ++rt)
            #pragma unroll
            for (int r = 0; r < 4; ++r) {
                int ee = w * 32 + rt * 16 + quad * 4 + r;
                float wv = part[rt][r] * __builtin_amdgcn_rcpf(ds_s[ee] + 1e-8f);
                float comp = (ml == 0) ? dx_s[ee] : ((ml == 1) ? dy_s[ee] : dz_s[ee]);
                u_s[ee * 3 + ml] = comp * wv;
            }
    }
    WFENCE;
    {   // contiguous 384B store per wave (in-wave DS ordering; no barrier needed)
        float* up = upd + (be0 + w * 32) * 3;
        up[lane] = u_s[w * 96 + lane];
        if (lane < 32) up[64 + lane] = u_s[w * 96 + 64 + lane];
    }
}

// light coord gather (R10-proven): xnext = xcur + (sum_p sgn*upd[e])/count
__global__ void k_coord(const float* __restrict__ xcur, float* __restrict__ xnext,
                        const float* __restrict__ upd,
                        const int* __restrict__ indptr, const int* __restrict__ adj) {
    int idx = blockIdx.x * 256 + threadIdx.x;   // B*N exact
    int b = idx / N_;
    int n = idx - b * N_;
    const float* ub = upd + (size_t)b * E_ * 3;
    int p0 = indptr[n], p1 = indptr[n + 1];
    float ax = 0.f, ay = 0.f, az = 0.f;
    for (int p = p0; p < p1; ++p) {
        int a = adj[p];
        int e = a >> 1;
        float sgn = (a & 1) ? 1.f : -1.f;
        ax += sgn * ub[e * 3 + 0];
        ay += sgn * ub[e * 3 + 1];
        az += sgn * ub[e * 3 + 2];
    }
    float rcnt = __builtin_amdgcn_rcpf((float)max(p1 - p0, 1));
    xnext[(size_t)idx * 3 + 0] = xcur[(size_t)idx * 3 + 0] + ax * rcnt;
    xnext[(size_t)idx * 3 + 1] = xcur[(size_t)idx * 3 + 1] + ay * rcnt;
    xnext[(size_t)idx * 3 + 2] = xcur[(size_t)idx * 3 + 2] + az * rcnt;
}

// 64 nodes/block, 256 threads = 4 waves x 16 rows.
// R14 delta: T14 gather prefetch extended depth-2 -> depth-3 (48 VGPRs held
// across GEMM1; budget 48+24 B-pipe+32 AGPR+~16 addr = ~120 <= (256,4) cap
// 128). ~40% of nodes (deg<=3) now hide their ENTIRE m16 gather under
// GEMM1's 32 MFMAs; the rest lose one exposed L2 round-trip. Consumption
// stays p-ascending -> bit-identical. R13's h-residual prefetch kept.
__global__ __launch_bounds__(256, 4) void k_node_mfma(
    float* __restrict__ h, _Float16* __restrict__ h16,
    const _Float16* __restrict__ m16,
    const int* __restrict__ indptr, const int* __restrict__ adj,
    const float* __restrict__ bn1, const _Float16* __restrict__ Wn1f,
    const float* __restrict__ bn2, const _Float16* __restrict__ Wn2f) {
    __shared__ _Float16 As[NPB * MRS];   // 17408 B
    int tid = threadIdx.x;
    int el = tid >> 2, q = tid & 3;
    int be = blockIdx.x * NPB + el;   // b*N + n
    int b = be / N_, n = be - b * N_;
    // stage h tile (fp16, wave-own rows)
    {
        const _Float16* hr = h16 + (size_t)be * H_;
        #pragma unroll
        for (int j = 0; j < 4; ++j)
            *(f16x8*)(As + el * MRS + q * 32 + j * 8) = *(const f16x8*)(hr + q * 32 + j * 8);
    }
    // T14 prefetch: first THREE adjacency entries' m16 slices (clamped)
    int p0 = indptr[n], p1 = indptr[n + 1];
    int d0 = p1 - p0;
    const _Float16* mbb = m16 + (size_t)b * E_ * H_;
    int ea = (d0 > 0) ? (adj[p0] >> 1) : 0;
    int eb = (d0 > 1) ? (adj[p0 + 1] >> 1) : ea;
    int ec = (d0 > 2) ? (adj[p0 + 2] >> 1) : ea;
    f16x8 va[4], vb[4], vc[4];
    load_row(va, mbb + (size_t)ea * H_ + q * 32);
    load_row(vb, mbb + (size_t)eb * H_ + q * 32);
    load_row(vc, mbb + (size_t)ec * H_ + q * 32);
    WFENCE;

    int lane = tid & 63, w = tid >> 6;
    int ml = lane & 15, quad = lane >> 4;
    _Float16* Asw = As + w * 16 * MRS;
    size_t be0 = (size_t)blockIdx.x * NPB;

    f32x4 acc[8];
    #pragma unroll
    for (int nt = 0; nt < 8; ++nt) {
        float bb = bn1[nt * 16 + ml];
        #pragma unroll
        for (int r = 0; r < 4; ++r) acc[nt][r] = bb;
    }
    mfma_gemm<MRS, 4>(Asw, Wn1f, acc, ml, quad, lane);     // + h @ Wn1a
    WFENCE;
    // agg gather -> As (overwrites h tile; wave-own rows; 4 threads/row)
    {
        float ag[4][8];
        #pragma unroll
        for (int j = 0; j < 4; ++j)
            #pragma unroll
            for (int i = 0; i < 8; ++i) ag[j][i] = 0.f;
        // consume prefetched rows (same p order as before -> bit-identical sums)
        if (d0 > 0) acc_row(ag, va);
        if (d0 > 1) acc_row(ag, vb);
        if (d0 > 2) acc_row(ag, vc);
        int p = p0 + 3;
        // chunk-2 pipeline: issue both rows' loads before accumulating either
        while (p + 2 <= p1) {
            int e1 = adj[p] >> 1, e2 = adj[p + 1] >> 1;
            f16x8 w1[4], w2[4];
            load_row(w1, mbb + (size_t)e1 * H_ + q * 32);
            load_row(w2, mbb + (size_t)e2 * H_ + q * 32);
            acc_row(ag, w1);
            acc_row(ag, w2);
            p += 2;
        }
        if (p < p1) {
            int e1 = adj[p] >> 1;
            f16x8 w1[4];
            load_row(w1, mbb + (size_t)e1 * H_ + q * 32);
            acc_row(ag, w1);
        }
        #pragma unroll
        for (int j = 0; j < 4; ++j) {
            f16x8 o;
            #pragma unroll
            for (int i = 0; i < 8; ++i) o[i] = (_Float16)ag[j][i];
            *(f16x8*)(As + el * MRS + q * 32 + j * 8) = o;
        }
    }
    WFENCE;
    mfma_gemm<MRS, 4>(Asw, Wn1f + 4 * 8 * 64 * 8, acc, ml, quad, lane);  // + agg @ Wn1b
    WFENCE;
    // u -> As (wave-own rows)
    #pragma unroll
    for (int nt = 0; nt < 8; ++nt)
        #pragma unroll
        for (int r = 0; r < 4; ++r)
            Asw[(quad * 4 + r) * MRS + nt * 16 + ml] = (_Float16)silu_f(acc[nt][r]);
    WFENCE;
    // R13: prefetch residual h at MFMA C-layout positions (32 scattered fp32);
    // issued before the Wn2 GEMM so L2 latency hides under the MFMAs.
    float hpre[8][4];
    #pragma unroll
    for (int nt = 0; nt < 8; ++nt)
        #pragma unroll
        for (int r = 0; r < 4; ++r) {
            int row = w * 16 + quad * 4 + r;
            hpre[nt][r] = h[(size_t)(be0 + row) * H_ + nt * 16 + ml];
        }
    WFENCE;
    f32x4 acc2[8];
    #pragma unroll
    for (int nt = 0; nt < 8; ++nt) {
        float bb = bn2[nt * 16 + ml];
        #pragma unroll
        for (int r = 0; r < 4; ++r) acc2[nt][r] = bb;
    }
    mfma_gemm<MRS, 4>(Asw, Wn2f, acc2, ml, quad, lane);
    // residual (prefetched fp32 h) + writeback h and h16
    #pragma unroll
    for (int nt = 0; nt < 8; ++nt)
        #pragma unroll
        for (int r = 0; r < 4; ++r) {
            int row = w * 16 + quad * 4 + r;
            size_t g = (size_t)(be0 + row) * H_ + nt * 16 + ml;
            float v = hpre[nt][r] + acc2[nt][r];
            h[g] = v;
            h16[g] = (_Float16)v;
        }
}

// out = silu(h16@Wo1+bo1)@Wo2 + bo2 + (xfin - xorig)
// R7-proven: GEMM phase = verbatim node-kernel pattern; epilogue = R4-verified
// red-buffer reduce (red[row*48 + ml*3 + j], summed over all 16 ml).
__global__ __launch_bounds__(256, 4) void k_out_mfma(
    const _Float16* __restrict__ h16, const float* __restrict__ xfin, const float* __restrict__ xorig,
    const _Float16* __restrict__ Wo1f, const float* __restrict__ bo1,
    const float* __restrict__ Wo2, const float* __restrict__ bo2,
    float* __restrict__ out) {
    __shared__ _Float16 As[64 * MRS];    // 17408 B
    __shared__ float red[64 * 48];       // 12288 B
    int tid = threadIdx.x;
    int el = tid >> 2, q = tid & 3;
    size_t be = (size_t)blockIdx.x * 64 + el;
    // stage h16 tile (node-kernel staging pattern verbatim; wave-own rows)
    {
        const _Float16* hr = h16 + be * H_;
        #pragma unroll
        for (int j = 0; j < 4; ++j)
            *(f16x8*)(As + el * MRS + q * 32 + j * 8) = *(const f16x8*)(hr + q * 32 + j * 8);
    }
    WFENCE;

    int lane = tid & 63, w = tid >> 6;
    int ml = lane & 15, quad = lane >> 4;
    _Float16* Asw = As + w * 16 * MRS;

    f32x4 acc[8];
    #pragma unroll
    for (int nt = 0; nt < 8; ++nt) {
        float bb = bo1[nt * 16 + ml];
        #pragma unroll
        for (int r = 0; r < 4; ++r) acc[nt][r] = bb;
    }
    mfma_gemm<MRS, 4>(Asw, Wo1f, acc, ml, quad, lane);   // h16 @ Wo1
    // per-lane Wo2 fold: lane (ml,quad) holds rows w*16+quad*4+r, cols nt*16+ml
    #pragma unroll
    for (int r = 0; r < 4; ++r) {
        float p0 = 0.f, p1 = 0.f, p2 = 0.f;
        #pragma unroll
        for (int nt = 0; nt < 8; ++nt) {
            float u = silu_f(acc[nt][r]);
            int col = nt * 16 + ml;
            p0 += u * Wo2[col * 3 + 0];
            p1 += u * Wo2[col * 3 + 1];
            p2 += u * Wo2[col * 3 + 2];
        }
        int row = w * 16 + quad * 4 + r;
        red[row * 48 + ml * 3 + 0] = p0;
        red[row * 48 + ml * 3 + 1] = p1;
        red[row * 48 + ml * 3 + 2] = p2;
    }
    __syncthreads();
    // R4-verified final reduce: 192 threads, sum the 16 partials per (row,jj)
    if (tid < 192) {
        int row = tid / 3, jj = tid - row * 3;
        float s = 0.f;
        #pragma unroll
        for (int cc = 0; cc < 16; ++cc) s += red[row * 48 + cc * 3 + jj];
        size_t grow = (size_t)blockIdx.x * 64 + row;
        out[grow * 3 + jj] = s + bo2[jj] + xfin[grow * 3 + jj] - xorig[grow * 3 + jj];
    }
}

// ---------------- launcher ----------------

extern "C" void kernel_launch(void* const* d_in, const int* in_sizes, int n_in,
                              void* d_out, int out_size, void* d_ws, size_t ws_size,
                              hipStream_t stream) {
    const float* x = (const float*)d_in[0];
    const float* t = (const float*)d_in[1];
    const int* atom_types = (const int*)d_in[2];
    const int* bond = (const int*)d_in[3];
    const float* emb_table = (const float*)d_in[4];
    const float* W_t1 = (const float*)d_in[5];
    const float* b_t1 = (const float*)d_in[6];
    const float* W_t2 = (const float*)d_in[7];
    const float* b_t2 = (const float*)d_in[8];
    const float* W_node = (const float*)d_in[9];
    const float* b_node = (const float*)d_in[10];
    const float* Wm1 = (const float*)d_in[11];
    const float* bm1 = (const float*)d_in[12];
    const float* Wm2 = (const float*)d_in[13];
    const float* bm2 = (const float*)d_in[14];
    const float* Wn1 = (const float*)d_in[15];
    const float* bn1 = (const float*)d_in[16];
    const float* Wn2 = (const float*)d_in[17];
    const float* bn2 = (const float*)d_in[18];
    const float* Wc1 = (const float*)d_in[19];
    const float* bc1 = (const float*)d_in[20];
    const float* Wc2 = (const float*)d_in[21];
    const float* W_o1 = (const float*)d_in[22];
    const float* b_o1 = (const float*)d_in[23];
    const float* W_o2 = (const float*)d_in[24];
    const float* b_o2 = (const float*)d_in[25];
    float* out = (float*)d_out;

    char* p = (char*)d_ws;
    auto alloc = [&](size_t bytes) -> void* {
        void* r = (void*)p;
        p += (bytes + 255) & ~(size_t)255;
        return r;
    };
    // ~211 MB total
    float* t_emb = (float*)alloc((size_t)B_ * H_ * 4);
    float* emb_proj = (float*)alloc((size_t)A_ * H_ * 4);
    int* deg = (int*)alloc((size_t)N_ * 4);
    int* indptr = (int*)alloc((size_t)(N_ + 1) * 4);
    int* cursor = (int*)alloc((size_t)N_ * 4);
    int* adj = (int*)alloc((size_t)2 * E_ * 4);
    float* xb0 = (float*)alloc((size_t)B_ * N_ * 3 * 4);
    float* xb1 = (float*)alloc((size_t)B_ * N_ * 3 * 4);
    float* upd = (float*)alloc((size_t)B_ * E_ * 3 * 4);
    float* h = (float*)alloc((size_t)B_ * N_ * H_ * 4);
    _Float16* h16 = (_Float16*)alloc((size_t)B_ * N_ * H_ * 2);
    _Float16* m16 = (_Float16*)alloc((size_t)B_ * E_ * H_ * 2);
    _Float16* Wm1f = (_Float16*)alloc((size_t)L_ * 256 * H_ * 2);
    _Float16* Wm2f = (_Float16*)alloc((size_t)L_ * H_ * H_ * 2);
    _Float16* Wc1f = (_Float16*)alloc((size_t)L_ * H_ * H_ * 2);
    _Float16* Wn1f = (_Float16*)alloc((size_t)L_ * 256 * H_ * 2);
    _Float16* Wn2f = (_Float16*)alloc((size_t)L_ * H_ * H_ * 2);
    _Float16* Wo1f = (_Float16*)alloc((size_t)H_ * H_ * 2);

    k_zero<<<(N_ + 255) / 256, 256, 0, stream>>>(deg, cursor);
    k_deg<<<(E_ + 255) / 256, 256, 0, stream>>>(bond, deg);
    k_scan<<<1, 1024, 0, stream>>>(deg, indptr);
    k_fill<<<(E_ + 255) / 256, 256, 0, stream>>>(bond, indptr, cursor, adj);
    k_temb<<<B_, 128, 0, stream>>>(t, W_t1, b_t1, W_t2, b_t2, t_emb);
    k_embproj<<<1, 512, 0, stream>>>(emb_table, W_node, b_node, emb_proj);
    k_hinit<<<(B_ * N_ * H_ / 4) / 256, 256, 0, stream>>>(atom_types, emb_proj, t_emb, h, h16);
    k_xcopy<<<(B_ * N_ * 3) / 256, 256, 0, stream>>>(x, xb0);
    // weight prep: one launch per weight type, layer via blockIdx.y
    k_wprepL<<<dim3(128, L_), 256, 0, stream>>>(Wm1, Wm1f, 256, 257 * H_);
    k_wprepL<<<dim3(64, L_), 256, 0, stream>>>(Wm2, Wm2f, 128, H_ * H_);
    k_wprepL<<<dim3(64, L_), 256, 0, stream>>>(Wc1, Wc1f, 128, H_ * H_);
    k_wprepL<<<dim3(128, L_), 256, 0, stream>>>(Wn1, Wn1f, 256, 2 * H_ * H_);
    k_wprepL<<<dim3(64, L_), 256, 0, stream>>>(Wn2, Wn2f, 128, H_ * H_);
    k_wprepL<<<dim3(64, 1), 256, 0, stream>>>(W_o1, Wo1f, 128, H_ * H_);

    float* xc = xb0;
    float* xn = xb1;
    for (int l = 0; l < L_; ++l) {
        k_edge_mfma<<<(B_ * E_) / EPB, 128, 0, stream>>>(
            h16, xc, bond,
            Wm1 + (size_t)l * 257 * H_, bm1 + l * H_, Wm1f + (size_t)l * 256 * H_,
            bm2 + l * H_, Wm2f + (size_t)l * H_ * H_,
            bc1 + l * H_, Wc1f + (size_t)l * H_ * H_,
            Wc2 + (size_t)l * H_, m16, upd);
        k_coord<<<(B_ * N_) / 256, 256, 0, stream>>>(xc, xn, upd, indptr, adj);
        k_node_mfma<<<(B_ * N_) / NPB, 256, 0, stream>>>(
            h, h16, m16, indptr, adj,
            bn1 + l * H_, Wn1f + (size_t)l * 256 * H_,
            bn2 + l * H_, Wn2f + (size_t)l * H_ * H_);
        float* tmp = xc; xc = xn; xn = tmp;
    }
    k_out_mfma<<<(B_ * N_) / 64, 256, 0, stream>>>(h16, xc, x, Wo1f, b_o1, W_o2, b_o2, out);
}

// Round 15
// 970.851 us; speedup vs baseline: 1.0139x; 1.0139x over previous
//
#include <hip/hip_runtime.h>
#include <math.h>

#define B_ 8
#define N_ 20000
#define E_ 40000
#define H_ 128
#define L_ 4
#define A_ 4
#define MRS 136   // fp16 LDS row stride (128+8), edge + node + out kernels
#define EPB 64    // edges per block (2 waves x 32 rows)
#define NPB 64    // nodes per block (4 waves x 16 rows)

// compiler-only memory fence: orders LDS ops across phases without s_barrier
#define WFENCE __asm__ __volatile__("" ::: "memory")

typedef _Float16 f16x8 __attribute__((ext_vector_type(8)));
typedef _Float16 f16x4v __attribute__((ext_vector_type(4)));
typedef float f32x4 __attribute__((ext_vector_type(4)));

// silu via raw v_rcp_f32 (~1 ulp) — avoids the IEEE fdiv expansion (~11 VALU inst)
__device__ __forceinline__ float silu_f(float x) {
    return x * __builtin_amdgcn_rcpf(1.f + __expf(-x));
}

// ---------------- setup kernels ----------------

__global__ void k_zero(int* __restrict__ deg, int* __restrict__ cursor) {
    int i = blockIdx.x * 256 + threadIdx.x;
    if (i < N_) { deg[i] = 0; cursor[i] = 0; }
}

__global__ void k_deg(const int* __restrict__ bond, int* __restrict__ deg) {
    int e = blockIdx.x * 256 + threadIdx.x;
    if (e < E_) {
        atomicAdd(&deg[bond[2 * e]], 1);
        atomicAdd(&deg[bond[2 * e + 1]], 1);
    }
}

__global__ void k_scan(const int* __restrict__ deg, int* __restrict__ indptr) {
    __shared__ int sums[1024];
    const int CH = (N_ + 1023) / 1024;  // 20
    int t = threadIdx.x;
    int s0 = t * CH;
    int s1 = min(s0 + CH, N_);
    int s = 0;
    for (int i = s0; i < s1; ++i) s += deg[i];
    sums[t] = s;
    __syncthreads();
    for (int off = 1; off < 1024; off <<= 1) {
        int v = (t >= off) ? sums[t - off] : 0;
        __syncthreads();
        sums[t] += v;
        __syncthreads();
    }
    int base = (t > 0) ? sums[t - 1] : 0;
    int run = base;
    for (int i = s0; i < s1; ++i) { indptr[i] = run; run += deg[i]; }
    if (s1 == N_ && s0 < N_) indptr[N_] = run;
}

__global__ void k_fill(const int* __restrict__ bond, const int* __restrict__ indptr,
                       int* __restrict__ cursor, int* __restrict__ adj) {
    int e = blockIdx.x * 256 + threadIdx.x;
    if (e < E_) {
        int s = bond[2 * e], d = bond[2 * e + 1];
        int ps = indptr[s] + atomicAdd(&cursor[s], 1);
        adj[ps] = (e << 1);        // node is src -> sign -
        int pd = indptr[d] + atomicAdd(&cursor[d], 1);
        adj[pd] = (e << 1) | 1;    // node is dst -> sign +
    }
}

// Convert W[K][128] fp32 -> B-fragment-layout fp16 for mfma_f32_16x16x32_f16.
// blockIdx.y = layer; strides passed per weight type.
__global__ void k_wprepL(const float* __restrict__ W, _Float16* __restrict__ Wf,
                         int K, int wstride) {
    int l = blockIdx.y;
    const float* Wl = W + (size_t)l * wstride;
    _Float16* Wfl = Wf + (size_t)l * K * 128;
    int idx = blockIdx.x * 256 + threadIdx.x;
    if (idx >= K * 128) return;
    int j = idx & 7, lane = (idx >> 3) & 63, nt = (idx >> 9) & 7, kt = idx >> 12;
    int k = kt * 32 + (lane >> 4) * 8 + j;
    int n = nt * 16 + (lane & 15);
    Wfl[idx] = (_Float16)Wl[k * 128 + n];
}

__global__ void k_temb(const float* __restrict__ tv,
                       const float* __restrict__ W1, const float* __restrict__ b1,
                       const float* __restrict__ W2, const float* __restrict__ b2,
                       float* __restrict__ t_emb) {
    __shared__ float te[64];
    __shared__ float h1[128];
    int b = blockIdx.x;
    int tid = threadIdx.x;
    float tval = tv[b];
    if (tid < 32) {
        float fr = __expf((float)tid * (-logf(10000.f) / 31.f));
        float a = tval * fr;
        te[tid] = sinf(a);
        te[tid + 32] = cosf(a);
    }
    __syncthreads();
    float acc = b1[tid];
    for (int k = 0; k < 64; ++k) acc += te[k] * W1[k * 128 + tid];
    h1[tid] = silu_f(acc);
    __syncthreads();
    float acc2 = b2[tid];
    for (int k = 0; k < 128; ++k) acc2 += h1[k] * W2[k * 128 + tid];
    t_emb[b * 128 + tid] = acc2;
}

__global__ void k_embproj(const float* __restrict__ emb, const float* __restrict__ W,
                          const float* __restrict__ bias, float* __restrict__ outp) {
    int tid = threadIdx.x;       // 512 threads
    int a = tid >> 7, j = tid & 127;
    float acc = bias[j];
    for (int k = 0; k < 128; ++k) acc += emb[a * 128 + k] * W[k * 128 + j];
    outp[a * 128 + j] = acc;
}

__global__ void k_hinit(const int* __restrict__ at, const float* __restrict__ embp,
                        const float* __restrict__ temb, float* __restrict__ h,
                        _Float16* __restrict__ h16) {
    size_t idx4 = (size_t)blockIdx.x * 256 + threadIdx.x;   // over B*N*H/4
    size_t e0 = idx4 * 4;
    int j = (int)(e0 % H_);
    size_t bn = e0 / H_;
    int n = (int)(bn % N_);
    int b = (int)(bn / N_);
    int a = at[n];
    float4 ep = *(const float4*)(embp + a * H_ + j);
    float4 tv = *(const float4*)(temb + b * H_ + j);
    float4 r = make_float4(ep.x + tv.x, ep.y + tv.y, ep.z + tv.z, ep.w + tv.w);
    ((float4*)h)[idx4] = r;
    f16x4v o;
    o[0] = (_Float16)r.x; o[1] = (_Float16)r.y; o[2] = (_Float16)r.z; o[3] = (_Float16)r.w;
    *(f16x4v*)(h16 + e0) = o;
}

__global__ void k_xcopy(const float* __restrict__ x, float* __restrict__ xb) {
    int i = blockIdx.x * 256 + threadIdx.x;  // 480000 exact
    xb[i] = x[i];
}

// ---------------- MFMA GEMM cores (wave-local) ----------------
// Single row-tile (16 rows/wave) — node + out kernels:
template <int RS, int KT>
__device__ __forceinline__ void mfma_gemm(const _Float16* Asw, const _Float16* __restrict__ Wf,
                                          f32x4 (&acc)[8], int ml, int quad, int lane) {
    #pragma unroll
    for (int kt = 0; kt < KT; ++kt) {
        f16x8 a = *(const f16x8*)(Asw + ml * RS + kt * 32 + quad * 8);
        #pragma unroll
        for (int nt = 0; nt < 8; ++nt) {
            f16x8 b = *(const f16x8*)(Wf + (((kt * 8 + nt) * 64 + lane) * 8));
            acc[nt] = __builtin_amdgcn_mfma_f32_16x16x32_f16(a, b, acc[nt], 0, 0, 0);
        }
    }
}

// Two row-tiles (32 rows/wave) sharing each B fragment — edge kernel:
template <int RS, int KT>
__device__ __forceinline__ void mfma_gemm2(const _Float16* Asw, const _Float16* __restrict__ Wf,
                                           f32x4 (&acc)[2][8], int ml, int quad, int lane) {
    #pragma unroll
    for (int kt = 0; kt < KT; ++kt) {
        f16x8 a0 = *(const f16x8*)(Asw + ml * RS + kt * 32 + quad * 8);
        f16x8 a1 = *(const f16x8*)(Asw + (16 + ml) * RS + kt * 32 + quad * 8);
        #pragma unroll
        for (int nt = 0; nt < 8; ++nt) {
            f16x8 b = *(const f16x8*)(Wf + (((kt * 8 + nt) * 64 + lane) * 8));
            acc[0][nt] = __builtin_amdgcn_mfma_f32_16x16x32_f16(a0, b, acc[0][nt], 0, 0, 0);
            acc[1][nt] = __builtin_amdgcn_mfma_f32_16x16x32_f16(a1, b, acc[1][nt], 0, 0, 0);
        }
    }
}

// gather helpers (node kernel): statically-indexed register rows (rule #20 safe)
__device__ __forceinline__ void load_row(f16x8 (&v)[4], const _Float16* mp) {
    #pragma unroll
    for (int j = 0; j < 4; ++j) v[j] = *(const f16x8*)(mp + j * 8);
}
__device__ __forceinline__ void acc_row(float (&ag)[4][8], const f16x8 (&v)[4]) {
    #pragma unroll
    for (int j = 0; j < 4; ++j)
        #pragma unroll
        for (int i = 0; i < 8; ++i) ag[j][i] += (float)v[j][i];
}

// ---------------- per-layer kernels ----------------

// 64 edges/block, 128 threads = 2 waves x 32 rows (R8 structure).
// R11-proven epilogue: upd[e][3] via LDS bounce + coalesced 384B/wave store.
// R13: m16 store after GEMM3's MFMAs.
__global__ __launch_bounds__(128, 3) void k_edge_mfma(
    const _Float16* __restrict__ h16, const float* __restrict__ xcur,
    const int* __restrict__ bond,
    const float* __restrict__ Wm1, const float* __restrict__ bm1,
    const _Float16* __restrict__ Wm1f,
    const float* __restrict__ bm2, const _Float16* __restrict__ Wm2f,
    const float* __restrict__ bc1, const _Float16* __restrict__ Wc1f,
    const float* __restrict__ Wc2,
    _Float16* __restrict__ m16, float* __restrict__ upd) {
    __shared__ _Float16 As[EPB * MRS];   // 17408 B
    __shared__ float ds_s[EPB];
    __shared__ float dx_s[EPB], dy_s[EPB], dz_s[EPB];   // +768 B
    __shared__ float u_s[EPB * 3];                      // +768 B
    int tid = threadIdx.x;
    int b = blockIdx.x & 7;              // batch -> XCD locality
    int e0 = (blockIdx.x >> 3) * EPB;    // chunk within batch (0..624)
    size_t be0 = (size_t)b * E_ + e0;

    int el = tid >> 1, q = tid & 1;      // 2 threads/row; rows are wave-own
    int2 sd = ((const int2*)bond)[e0 + el];
    int s = sd.x, d = sd.y;

    // issue BOTH gathers now (T14): ps consumed immediately, pd held across GEMM1a
    const _Float16* hs = h16 + ((size_t)b * N_ + s) * H_ + q * 64;
    const _Float16* hd = h16 + ((size_t)b * N_ + d) * H_ + q * 64;
    f16x8 ps[8], pd[8];
    #pragma unroll
    for (int j = 0; j < 8; ++j) ps[j] = *(const f16x8*)(hs + j * 8);
    #pragma unroll
    for (int j = 0; j < 8; ++j) pd[j] = *(const f16x8*)(hd + j * 8);
    if (q == 0) {
        const float* xs = xcur + ((size_t)b * N_ + s) * 3;
        const float* xd = xcur + ((size_t)b * N_ + d) * 3;
        float dx = xd[0] - xs[0], dy = xd[1] - xs[1], dz = xd[2] - xs[2];
        ds_s[el] = sqrtf(dx * dx + dy * dy + dz * dz);
        dx_s[el] = dx; dy_s[el] = dy; dz_s[el] = dz;
    }
    {   // stage h_src
        _Float16* ap = As + el * MRS + q * 64;
        #pragma unroll
        for (int j = 0; j < 8; ++j) *(f16x8*)(ap + j * 8) = ps[j];
    }
    WFENCE;

    int lane = tid & 63, w = tid >> 6;   // wave owns rows w*32..w*32+31
    int ml = lane & 15, quad = lane >> 4;
    _Float16* Asw = As + w * 32 * MRS;
    const float* wd = Wm1 + 256 * H_;

    f32x4 acc[2][8];
    // acc = bm1 + dist*wd
    #pragma unroll
    for (int nt = 0; nt < 8; ++nt) {
        int col = nt * 16 + ml;
        float bb = bm1[col];
        float ww = wd[col];
        #pragma unroll
        for (int rt = 0; rt < 2; ++rt)
            #pragma unroll
            for (int r = 0; r < 4; ++r)
                acc[rt][nt][r] = bb + ds_s[w * 32 + rt * 16 + quad * 4 + r] * ww;
    }
    mfma_gemm2<MRS, 4>(Asw, Wm1f, acc, ml, quad, lane);              // + h_s @ Wm1[0:128]
    WFENCE;
    {   // restage h_dst from prefetched regs (wave-own rows; in-order DS pipe)
        _Float16* ap = As + el * MRS + q * 64;
        #pragma unroll
        for (int j = 0; j < 8; ++j) *(f16x8*)(ap + j * 8) = pd[j];
    }
    WFENCE;
    mfma_gemm2<MRS, 4>(Asw, Wm1f + 4 * 8 * 64 * 8, acc, ml, quad, lane);  // + h_d @ Wm1[128:256]
    WFENCE;
    // repack m1 = silu(acc) -> As (wave-own rows)
    #pragma unroll
    for (int rt = 0; rt < 2; ++rt)
        #pragma unroll
        for (int nt = 0; nt < 8; ++nt)
            #pragma unroll
            for (int r = 0; r < 4; ++r)
                Asw[(rt * 16 + quad * 4 + r) * MRS + nt * 16 + ml] = (_Float16)silu_f(acc[rt][nt][r]);
    WFENCE;

    // ---- GEMM2: m = silu(m1 @ Wm2 + bm2)
    #pragma unroll
    for (int nt = 0; nt < 8; ++nt) {
        float bb = bm2[nt * 16 + ml];
        #pragma unroll
        for (int rt = 0; rt < 2; ++rt)
            #pragma unroll
            for (int r = 0; r < 4; ++r) acc[rt][nt][r] = bb;
    }
    mfma_gemm2<MRS, 4>(Asw, Wm2f, acc, ml, quad, lane);
    WFENCE;
    // repack m -> As (overwrites m1; this wave's GEMM2 reads are done)
    #pragma unroll
    for (int rt = 0; rt < 2; ++rt)
        #pragma unroll
        for (int nt = 0; nt < 8; ++nt)
            #pragma unroll
            for (int r = 0; r < 4; ++r)
                Asw[(rt * 16 + quad * 4 + r) * MRS + nt * 16 + ml] = (_Float16)silu_f(acc[rt][nt][r]);
    WFENCE;

    // ---- GEMM3: cw = silu(m @ Wc1 + bc1) @ Wc2  (B-loads issue first)
    #pragma unroll
    for (int nt = 0; nt < 8; ++nt) {
        float bb = bc1[nt * 16 + ml];
        #pragma unroll
        for (int rt = 0; rt < 2; ++rt)
            #pragma unroll
            for (int r = 0; r < 4; ++r) acc[rt][nt][r] = bb;
    }
    mfma_gemm2<MRS, 4>(Asw, Wc1f, acc, ml, quad, lane);
    // m16 store: overlaps the Wc2 fold + butterfly below
    #pragma unroll
    for (int j = 0; j < 8; ++j)
        *(f16x8*)(m16 + (be0 + el) * H_ + q * 64 + j * 8) =
            *(const f16x8*)(As + el * MRS + q * 64 + j * 8);
    float part[2][4] = {{0.f, 0.f, 0.f, 0.f}, {0.f, 0.f, 0.f, 0.f}};
    #pragma unroll
    for (int nt = 0; nt < 8; ++nt) {
        float wv = Wc2[nt * 16 + ml];
        #pragma unroll
        for (int rt = 0; rt < 2; ++rt)
            #pragma unroll
            for (int r = 0; r < 4; ++r) part[rt][r] += silu_f(acc[rt][nt][r]) * wv;
    }
    #pragma unroll
    for (int off = 1; off < 16; off <<= 1)
        #pragma unroll
        for (int rt = 0; rt < 2; ++rt)
            #pragma unroll
            for (int r = 0; r < 4; ++r) part[rt][r] += __shfl_xor(part[rt][r], off, 64);
    // upd: LDS bounce (wave-own region [w*96, w*96+96)) then coalesced store.
    if (ml < 3) {
        #pragma unroll
        for (int rt = 0; rt < 2; ++rt)
            #pragma unroll
            for (int r = 0; r < 4; ++r) {
                int ee = w * 32 + rt * 16 + quad * 4 + r;
                float wv = part[rt][r] * __builtin_amdgcn_rcpf(ds_s[ee] + 1e-8f);
                float comp = (ml == 0) ? dx_s[ee] : ((ml == 1) ? dy_s[ee] : dz_s[ee]);
                u_s[ee * 3 + ml] = comp * wv;
            }
    }
    WFENCE;
    {   // contiguous 384B store per wave (in-wave DS ordering; no barrier needed)
        float* up = upd + (be0 + w * 32) * 3;
        up[lane] = u_s[w * 96 + lane];
        if (lane < 32) up[64 + lane] = u_s[w * 96 + 64 + lane];
    }
}

// light coord gather (R10-proven): xnext = xcur + (sum_p sgn*upd[e])/count
__global__ void k_coord(const float* __restrict__ xcur, float* __restrict__ xnext,
                        const float* __restrict__ upd,
                        const int* __restrict__ indptr, const int* __restrict__ adj) {
    int idx = blockIdx.x * 256 + threadIdx.x;   // B*N exact
    int b = idx / N_;
    int n = idx - b * N_;
    const float* ub = upd + (size_t)b * E_ * 3;
    int p0 = indptr[n], p1 = indptr[n + 1];
    float ax = 0.f, ay = 0.f, az = 0.f;
    for (int p = p0; p < p1; ++p) {
        int a = adj[p];
        int e = a >> 1;
        float sgn = (a & 1) ? 1.f : -1.f;
        ax += sgn * ub[e * 3 + 0];
        ay += sgn * ub[e * 3 + 1];
        az += sgn * ub[e * 3 + 2];
    }
    float rcnt = __builtin_amdgcn_rcpf((float)max(p1 - p0, 1));
    xnext[(size_t)idx * 3 + 0] = xcur[(size_t)idx * 3 + 0] + ax * rcnt;
    xnext[(size_t)idx * 3 + 1] = xcur[(size_t)idx * 3 + 1] + ay * rcnt;
    xnext[(size_t)idx * 3 + 2] = xcur[(size_t)idx * 3 + 2] + az * rcnt;
}

// 64 nodes/block, 256 threads = 4 waves x 16 rows (R13 state — depth-2
// prefetch; R14's depth-3 was neutral-to-negative and is reverted).
// R8-proven: T14 prefetch of first 2 adjacency rows + chunk-2 register
// pipeline (accumulation order unchanged -> bit-identical). R13's
// h-residual prefetch kept.
__global__ __launch_bounds__(256, 4) void k_node_mfma(
    float* __restrict__ h, _Float16* __restrict__ h16,
    const _Float16* __restrict__ m16,
    const int* __restrict__ indptr, const int* __restrict__ adj,
    const float* __restrict__ bn1, const _Float16* __restrict__ Wn1f,
    const float* __restrict__ bn2, const _Float16* __restrict__ Wn2f) {
    __shared__ _Float16 As[NPB * MRS];   // 17408 B
    int tid = threadIdx.x;
    int el = tid >> 2, q = tid & 3;
    int be = blockIdx.x * NPB + el;   // b*N + n
    int b = be / N_, n = be - b * N_;
    // stage h tile (fp16, wave-own rows)
    {
        const _Float16* hr = h16 + (size_t)be * H_;
        #pragma unroll
        for (int j = 0; j < 4; ++j)
            *(f16x8*)(As + el * MRS + q * 32 + j * 8) = *(const f16x8*)(hr + q * 32 + j * 8);
    }
    // T14 prefetch: first two adjacency entries' m16 slices (clamped; deg may be 0)
    int p0 = indptr[n], p1 = indptr[n + 1];
    int d0 = p1 - p0;
    const _Float16* mbb = m16 + (size_t)b * E_ * H_;
    int ea = (d0 > 0) ? (adj[p0] >> 1) : 0;
    int eb = (d0 > 1) ? (adj[p0 + 1] >> 1) : ea;
    f16x8 va[4], vb[4];
    load_row(va, mbb + (size_t)ea * H_ + q * 32);
    load_row(vb, mbb + (size_t)eb * H_ + q * 32);
    WFENCE;

    int lane = tid & 63, w = tid >> 6;
    int ml = lane & 15, quad = lane >> 4;
    _Float16* Asw = As + w * 16 * MRS;
    size_t be0 = (size_t)blockIdx.x * NPB;

    f32x4 acc[8];
    #pragma unroll
    for (int nt = 0; nt < 8; ++nt) {
        float bb = bn1[nt * 16 + ml];
        #pragma unroll
        for (int r = 0; r < 4; ++r) acc[nt][r] = bb;
    }
    mfma_gemm<MRS, 4>(Asw, Wn1f, acc, ml, quad, lane);     // + h @ Wn1a
    WFENCE;
    // agg gather -> As (overwrites h tile; wave-own rows; 4 threads/row)
    {
        float ag[4][8];
        #pragma unroll
        for (int j = 0; j < 4; ++j)
            #pragma unroll
            for (int i = 0; i < 8; ++i) ag[j][i] = 0.f;
        // consume prefetched rows (same p order as before -> bit-identical sums)
        if (d0 > 0) acc_row(ag, va);
        if (d0 > 1) acc_row(ag, vb);
        int p = p0 + 2;
        // chunk-2 pipeline: issue both rows' loads before accumulating either
        while (p + 2 <= p1) {
            int e1 = adj[p] >> 1, e2 = adj[p + 1] >> 1;
            f16x8 w1[4], w2[4];
            load_row(w1, mbb + (size_t)e1 * H_ + q * 32);
            load_row(w2, mbb + (size_t)e2 * H_ + q * 32);
            acc_row(ag, w1);
            acc_row(ag, w2);
            p += 2;
        }
        if (p < p1) {
            int e1 = adj[p] >> 1;
            f16x8 w1[4];
            load_row(w1, mbb + (size_t)e1 * H_ + q * 32);
            acc_row(ag, w1);
        }
        #pragma unroll
        for (int j = 0; j < 4; ++j) {
            f16x8 o;
            #pragma unroll
            for (int i = 0; i < 8; ++i) o[i] = (_Float16)ag[j][i];
            *(f16x8*)(As + el * MRS + q * 32 + j * 8) = o;
        }
    }
    WFENCE;
    mfma_gemm<MRS, 4>(Asw, Wn1f + 4 * 8 * 64 * 8, acc, ml, quad, lane);  // + agg @ Wn1b
    WFENCE;
    // u -> As (wave-own rows)
    #pragma unroll
    for (int nt = 0; nt < 8; ++nt)
        #pragma unroll
        for (int r = 0; r < 4; ++r)
            Asw[(quad * 4 + r) * MRS + nt * 16 + ml] = (_Float16)silu_f(acc[nt][r]);
    WFENCE;
    // R13: prefetch residual h at MFMA C-layout positions (32 scattered fp32);
    // issued before the Wn2 GEMM so L2 latency hides under the MFMAs.
    float hpre[8][4];
    #pragma unroll
    for (int nt = 0; nt < 8; ++nt)
        #pragma unroll
        for (int r = 0; r < 4; ++r) {
            int row = w * 16 + quad * 4 + r;
            hpre[nt][r] = h[(size_t)(be0 + row) * H_ + nt * 16 + ml];
        }
    WFENCE;
    f32x4 acc2[8];
    #pragma unroll
    for (int nt = 0; nt < 8; ++nt) {
        float bb = bn2[nt * 16 + ml];
        #pragma unroll
        for (int r = 0; r < 4; ++r) acc2[nt][r] = bb;
    }
    mfma_gemm<MRS, 4>(Asw, Wn2f, acc2, ml, quad, lane);
    // residual (prefetched fp32 h) + writeback h and h16
    #pragma unroll
    for (int nt = 0; nt < 8; ++nt)
        #pragma unroll
        for (int r = 0; r < 4; ++r) {
            int row = w * 16 + quad * 4 + r;
            size_t g = (size_t)(be0 + row) * H_ + nt * 16 + ml;
            float v = hpre[nt][r] + acc2[nt][r];
            h[g] = v;
            h16[g] = (_Float16)v;
        }
}

// out = silu(h16@Wo1+bo1)@Wo2 + bo2 + (xfin - xorig)
// R7-proven: GEMM phase = verbatim node-kernel pattern; epilogue = R4-verified
// red-buffer reduce (red[row*48 + ml*3 + j], summed over all 16 ml).
__global__ __launch_bounds__(256, 4) void k_out_mfma(
    const _Float16* __restrict__ h16, const float* __restrict__ xfin, const float* __restrict__ xorig,
    const _Float16* __restrict__ Wo1f, const float* __restrict__ bo1,
    const float* __restrict__ Wo2, const float* __restrict__ bo2,
    float* __restrict__ out) {
    __shared__ _Float16 As[64 * MRS];    // 17408 B
    __shared__ float red[64 * 48];       // 12288 B
    int tid = threadIdx.x;
    int el = tid >> 2, q = tid & 3;
    size_t be = (size_t)blockIdx.x * 64 + el;
    // stage h16 tile (node-kernel staging pattern verbatim; wave-own rows)
    {
        const _Float16* hr = h16 + be * H_;
        #pragma unroll
        for (int j = 0; j < 4; ++j)
            *(f16x8*)(As + el * MRS + q * 32 + j * 8) = *(const f16x8*)(hr + q * 32 + j * 8);
    }
    WFENCE;

    int lane = tid & 63, w = tid >> 6;
    int ml = lane & 15, quad = lane >> 4;
    _Float16* Asw = As + w * 16 * MRS;

    f32x4 acc[8];
    #pragma unroll
    for (int nt = 0; nt < 8; ++nt) {
        float bb = bo1[nt * 16 + ml];
        #pragma unroll
        for (int r = 0; r < 4; ++r) acc[nt][r] = bb;
    }
    mfma_gemm<MRS, 4>(Asw, Wo1f, acc, ml, quad, lane);   // h16 @ Wo1
    // per-lane Wo2 fold: lane (ml,quad) holds rows w*16+quad*4+r, cols nt*16+ml
    #pragma unroll
    for (int r = 0; r < 4; ++r) {
        float p0 = 0.f, p1 = 0.f, p2 = 0.f;
        #pragma unroll
        for (int nt = 0; nt < 8; ++nt) {
            float u = silu_f(acc[nt][r]);
            int col = nt * 16 + ml;
            p0 += u * Wo2[col * 3 + 0];
            p1 += u * Wo2[col * 3 + 1];
            p2 += u * Wo2[col * 3 + 2];
        }
        int row = w * 16 + quad * 4 + r;
        red[row * 48 + ml * 3 + 0] = p0;
        red[row * 48 + ml * 3 + 1] = p1;
        red[row * 48 + ml * 3 + 2] = p2;
    }
    __syncthreads();
    // R4-verified final reduce: 192 threads, sum the 16 partials per (row,jj)
    if (tid < 192) {
        int row = tid / 3, jj = tid - row * 3;
        float s = 0.f;
        #pragma unroll
        for (int cc = 0; cc < 16; ++cc) s += red[row * 48 + cc * 3 + jj];
        size_t grow = (size_t)blockIdx.x * 64 + row;
        out[grow * 3 + jj] = s + bo2[jj] + xfin[grow * 3 + jj] - xorig[grow * 3 + jj];
    }
}

// ---------------- launcher ----------------

extern "C" void kernel_launch(void* const* d_in, const int* in_sizes, int n_in,
                              void* d_out, int out_size, void* d_ws, size_t ws_size,
                              hipStream_t stream) {
    const float* x = (const float*)d_in[0];
    const float* t = (const float*)d_in[1];
    const int* atom_types = (const int*)d_in[2];
    const int* bond = (const int*)d_in[3];
    const float* emb_table = (const float*)d_in[4];
    const float* W_t1 = (const float*)d_in[5];
    const float* b_t1 = (const float*)d_in[6];
    const float* W_t2 = (const float*)d_in[7];
    const float* b_t2 = (const float*)d_in[8];
    const float* W_node = (const float*)d_in[9];
    const float* b_node = (const float*)d_in[10];
    const float* Wm1 = (const float*)d_in[11];
    const float* bm1 = (const float*)d_in[12];
    const float* Wm2 = (const float*)d_in[13];
    const float* bm2 = (const float*)d_in[14];
    const float* Wn1 = (const float*)d_in[15];
    const float* bn1 = (const float*)d_in[16];
    const float* Wn2 = (const float*)d_in[17];
    const float* bn2 = (const float*)d_in[18];
    const float* Wc1 = (const float*)d_in[19];
    const float* bc1 = (const float*)d_in[20];
    const float* Wc2 = (const float*)d_in[21];
    const float* W_o1 = (const float*)d_in[22];
    const float* b_o1 = (const float*)d_in[23];
    const float* W_o2 = (const float*)d_in[24];
    const float* b_o2 = (const float*)d_in[25];
    float* out = (float*)d_out;

    char* p = (char*)d_ws;
    auto alloc = [&](size_t bytes) -> void* {
        void* r = (void*)p;
        p += (bytes + 255) & ~(size_t)255;
        return r;
    };
    // ~211 MB total
    float* t_emb = (float*)alloc((size_t)B_ * H_ * 4);
    float* emb_proj = (float*)alloc((size_t)A_ * H_ * 4);
    int* deg = (int*)alloc((size_t)N_ * 4);
    int* indptr = (int*)alloc((size_t)(N_ + 1) * 4);
    int* cursor = (int*)alloc((size_t)N_ * 4);
    int* adj = (int*)alloc((size_t)2 * E_ * 4);
    float* xb0 = (float*)alloc((size_t)B_ * N_ * 3 * 4);
    float* xb1 = (float*)alloc((size_t)B_ * N_ * 3 * 4);
    float* upd = (float*)alloc((size_t)B_ * E_ * 3 * 4);
    float* h = (float*)alloc((size_t)B_ * N_ * H_ * 4);
    _Float16* h16 = (_Float16*)alloc((size_t)B_ * N_ * H_ * 2);
    _Float16* m16 = (_Float16*)alloc((size_t)B_ * E_ * H_ * 2);
    _Float16* Wm1f = (_Float16*)alloc((size_t)L_ * 256 * H_ * 2);
    _Float16* Wm2f = (_Float16*)alloc((size_t)L_ * H_ * H_ * 2);
    _Float16* Wc1f = (_Float16*)alloc((size_t)L_ * H_ * H_ * 2);
    _Float16* Wn1f = (_Float16*)alloc((size_t)L_ * 256 * H_ * 2);
    _Float16* Wn2f = (_Float16*)alloc((size_t)L_ * H_ * H_ * 2);
    _Float16* Wo1f = (_Float16*)alloc((size_t)H_ * H_ * 2);

    k_zero<<<(N_ + 255) / 256, 256, 0, stream>>>(deg, cursor);
    k_deg<<<(E_ + 255) / 256, 256, 0, stream>>>(bond, deg);
    k_scan<<<1, 1024, 0, stream>>>(deg, indptr);
    k_fill<<<(E_ + 255) / 256, 256, 0, stream>>>(bond, indptr, cursor, adj);
    k_temb<<<B_, 128, 0, stream>>>(t, W_t1, b_t1, W_t2, b_t2, t_emb);
    k_embproj<<<1, 512, 0, stream>>>(emb_table, W_node, b_node, emb_proj);
    k_hinit<<<(B_ * N_ * H_ / 4) / 256, 256, 0, stream>>>(atom_types, emb_proj, t_emb, h, h16);
    k_xcopy<<<(B_ * N_ * 3) / 256, 256, 0, stream>>>(x, xb0);
    // weight prep: one launch per weight type, layer via blockIdx.y
    k_wprepL<<<dim3(128, L_), 256, 0, stream>>>(Wm1, Wm1f, 256, 257 * H_);
    k_wprepL<<<dim3(64, L_), 256, 0, stream>>>(Wm2, Wm2f, 128, H_ * H_);
    k_wprepL<<<dim3(64, L_), 256, 0, stream>>>(Wc1, Wc1f, 128, H_ * H_);
    k_wprepL<<<dim3(128, L_), 256, 0, stream>>>(Wn1, Wn1f, 256, 2 * H_ * H_);
    k_wprepL<<<dim3(64, L_), 256, 0, stream>>>(Wn2, Wn2f, 128, H_ * H_);
    k_wprepL<<<dim3(64, 1), 256, 0, stream>>>(W_o1, Wo1f, 128, H_ * H_);

    float* xc = xb0;
    float* xn = xb1;
    for (int l = 0; l < L_; ++l) {
        k_edge_mfma<<<(B_ * E_) / EPB, 128, 0, stream>>>(
            h16, xc, bond,
            Wm1 + (size_t)l * 257 * H_, bm1 + l * H_, Wm1f + (size_t)l * 256 * H_,
            bm2 + l * H_, Wm2f + (size_t)l * H_ * H_,
            bc1 + l * H_, Wc1f + (size_t)l * H_ * H_,
            Wc2 + (size_t)l * H_, m16, upd);
        k_coord<<<(B_ * N_) / 256, 256, 0, stream>>>(xc, xn, upd, indptr, adj);
        k_node_mfma<<<(B_ * N_) / NPB, 256, 0, stream>>>(
            h, h16, m16, indptr, adj,
            bn1 + l * H_, Wn1f + (size_t)l * 256 * H_,
            bn2 + l * H_, Wn2f + (size_t)l * H_ * H_);
        float* tmp = xc; xc = xn; xn = tmp;
    }
    k_out_mfma<<<(B_ * N_) / 64, 256, 0, stream>>>(h16, xc, x, Wo1f, b_o1, W_o2, b_o2, out);
}